// Round 10
// baseline (205.440 us; speedup 1.0000x reference)
//
#include <hip/hip_runtime.h>
#include <cstdint>
#include <cstddef>

// Problem constants (fixed by reference setup_inputs)
#define B_   8
#define D_   512
#define T_   2048
#define K_   8192
#define BT_  (B_ * T_)               // 16384 queries
#define NQ_  ((size_t)B_ * D_ * T_)  // 8388608 quantized elements

typedef _Float16 f16x8 __attribute__((ext_vector_type(8)));
typedef _Float16 f16x4 __attribute__((ext_vector_type(4)));
typedef float    f32x4 __attribute__((ext_vector_type(4)));
typedef unsigned long long u64;
typedef unsigned int u32;

// ws layout (bytes)
#define WS_SLOTS_OFF    0                        // u64[3*16384] = 393216
#define WS_FIDX_OFF     393216                   // u32[16384]   = 65536
#define WS_PART_OFF     458752                   // f32[512] (unused, kept for layout)
#define WS_E2_OFF       460800                   // f32[8192]
#define WS_XH_OFF       524288                   // f16[BT*512]  = 16777216
#define WS_XL_OFF       (WS_XH_OFF + 16777216)
#define WS_CH_OFF       (WS_XL_OFF + 16777216)   // f16[K*512]   = 8388608
#define WS_NEEDED       ((size_t)WS_CH_OFF + 8388608)   // ~42.5 MB

__device__ __forceinline__ void gload_lds16(const void* g, void* l) {
    __builtin_amdgcn_global_load_lds(
        (const __attribute__((address_space(1))) void*)g,
        (__attribute__((address_space(3))) void*)l, 16, 0, 0);
}

// monotone float -> uint key (handles negatives; preserves <) — fallback path only
__device__ __forceinline__ u32 fkey(float f) {
    u32 u = __float_as_uint(f);
    u ^= (u32)((int)u >> 31) | 0x80000000u;
    return u;
}
__device__ __forceinline__ u64 umin64(u64 a, u64 b) { return a < b ? a : b; }
__device__ __forceinline__ u64 umax64(u64 a, u64 b) { return a > b ? a : b; }

// ---------------- fused codebook prep: ch (f16 hi) + e2 in ONE cb pass ----------------
// wave per row: lane reads 8 floats (2x float4), writes f16x8, shfl-reduces e2.
__global__ __launch_bounds__(256) void k_prepcb(const float* __restrict__ cb,
                                                _Float16* __restrict__ ch,
                                                float* __restrict__ e2) {
    const int wid = threadIdx.x >> 6, lane = threadIdx.x & 63;
    const int row = blockIdx.x * 4 + wid;                    // grid 2048
    const float4* src = (const float4*)(cb + (size_t)row * D_ + lane * 8);
    float4 a = src[0], b = src[1];
    f16x8 h;
    h[0] = (_Float16)a.x; h[1] = (_Float16)a.y;
    h[2] = (_Float16)a.z; h[3] = (_Float16)a.w;
    h[4] = (_Float16)b.x; h[5] = (_Float16)b.y;
    h[6] = (_Float16)b.z; h[7] = (_Float16)b.w;
    *(f16x8*)(ch + (size_t)row * D_ + lane * 8) = h;
    float s = a.x * a.x;
    s = fmaf(a.y, a.y, s); s = fmaf(a.z, a.z, s); s = fmaf(a.w, a.w, s);
    s = fmaf(b.x, b.x, s); s = fmaf(b.y, b.y, s);
    s = fmaf(b.z, b.z, s); s = fmaf(b.w, b.w, s);
#pragma unroll
    for (int st = 1; st < 64; st <<= 1) s += __shfl_xor(s, st);
    if (lane == 0) e2[row] = s;
}

// ---------------- e2 only (fallback path, when ws can't hold ch) ----------------
__global__ __launch_bounds__(256) void k_e2(const float* __restrict__ cb,
                                            float* __restrict__ e2) {
    int k = blockIdx.x * 256 + threadIdx.x;
    const float4* row = (const float4*)(cb + (size_t)k * D_);
    float s = 0.f;
#pragma unroll 4
    for (int i = 0; i < D_ / 4; ++i) {
        float4 v = row[i];
        s = fmaf(v.x, v.x, s); s = fmaf(v.y, v.y, s);
        s = fmaf(v.z, v.z, s); s = fmaf(v.w, v.w, s);
    }
    e2[k] = s;
}

// ---------------- transpose+split x: [B,D,T] fp32 -> [BT,D] f16 hi/lo ----------------
// reads vectorized: 4 x float4 (64B contiguous per thread); writes coalesced over dl.
__global__ __launch_bounds__(256) void k_splitx(const float* __restrict__ x,
                                                _Float16* __restrict__ xh,
                                                _Float16* __restrict__ xl) {
    int b  = blockIdx.z;
    int d0 = blockIdx.y * 64;
    int t0 = blockIdx.x * 64;
    int dl = threadIdx.x & 63;
    int tq = threadIdx.x >> 6;
    const float* px = x + ((size_t)b * D_ + (d0 + dl)) * T_ + t0 + tq * 16;
#pragma unroll
    for (int i = 0; i < 4; ++i) {
        float4 v = *(const float4*)(px + i * 4);
#pragma unroll
        for (int j = 0; j < 4; ++j) {
            float vv = (j == 0) ? v.x : (j == 1) ? v.y : (j == 2) ? v.z : v.w;
            _Float16 h = (_Float16)vv;
            float lo = vv - (float)h;            // exact residual
            _Float16 l = (_Float16)lo;
            size_t row = (size_t)b * T_ + t0 + tq * 16 + i * 4 + j;
            xh[row * D_ + d0 + dl] = h;          // coalesced across lanes
            xl[row * D_ + d0 + dl] = l;
        }
    }
}

// ---------------- hi-only MFMA screening GEMM + deferred top-2 -> global top-3 ------
// screen key(q,c) = max(0.5*e2[c] - dot(xh_q, ch_c), 1.0) -> raw uint compare
// monotone. Packed u32 candidate: (bits & 0xFFFFFC00) | 10-bit local id
// (ns|wc|n|lr) == lexicographic first-min.
//
// Round-10: FINE-GRAIN 4-MFMA MICRO-CLUSTERS on the R5/R9 skeleton. R9 theory:
// the plateau's mechanism is aggregate LDS contention at slab start — after the
// barrier all 8 waves front-load 8 reads before their first 16-MFMA cluster;
// LDS services ~round-robin so every wave's first cluster is ready only after
// ~770 cy (matrix idle), then 64 MFMAs run with no reads pending (LDS idle):
// alternation re-emerges regardless of within-wave order (R3/R6 kept 8-16 read
// batches, never reduced reads-before-first-MFMA). Fix: first MFMA after FIVE
// reads (af0 + bf0..3); each following 4-MFMA cluster is preceded by exactly
// the one read it unblocks (af1, af2, af3, then bg0..3); sched_barrier(0) pins
// each micro-phase; stage split 2+2 unchanged. Accumulation order per acc[m][n]
// is BIT-IDENTICAL to R5 (m-outer, bf then bg). Ring-4, counted vmcnt(8),
// paired-row swizzle (0 conflicts), one barrier/slab — all unchanged.
__global__ __launch_bounds__(512, 2)
void k_hi_argmin(const _Float16* __restrict__ xh, const _Float16* __restrict__ ch,
                 const float* __restrict__ e2, u64* __restrict__ slots) {
    __shared__ char smem[131072];                // ring of 4 x (A 16KB | B 16KB)
    __shared__ u32 stop[256][2][2];              // per-query per-wc top-2 (packed u32)
    __shared__ float e2s[1024];                  // this block's e2 slice

    const int tid = threadIdx.x;
    // grid 512 = 8 xcd x 8 mtiles x 8 nsplit. XCD gets contiguous m-range (A L2-resident).
    const int xcd = blockIdx.x & 7;
    const int bi  = blockIdx.x >> 3;             // 0..63
    const int m_  = bi >> 3;                     // 0..7
    const int nblk = bi & 7;                     // 0..7
    const int mbase  = (xcd * 8 + m_) * 256;
    const int nstart = nblk * 1024;              // this block scans 1024 codes (4 subtiles)

    const int lane = tid & 63;
    const int wid  = tid >> 6;                   // 0..7
    const int wr = wid & 3, wc = wid >> 2;       // wave quadrant 64q x 128c
    const int lr = lane & 15, lg = lane >> 4;

    // init per-block top-2 table + stage e2 slice (no VMEM later in the loop)
    {
        u32* p = (u32*)stop;
        p[tid] = ~0u; p[tid + 512] = ~0u;
        *(float2*)&e2s[tid * 2] = *(const float2*)&e2[nstart + tid * 2];
    }
    __syncthreads();

    // ---- staging geometry: per wave 64 rows x 64 B per slab; 4 gloads x 16 rows ----
    // inverse-swizzled global source: lane L -> q=L>>3, u=(L&7)^q,
    // row = 2q + (u>>2), slot = u&3. (LDS dest stays linear: base + L*16.)
    const bool isA = wid < 4;
    const int q8 = lane >> 3;                    // 0..7
    const int u8 = (lane & 7) ^ q8;
    const int srow2 = (u8 >> 2) & 1;
    const int sslot = u8 & 3;
    const char* gs0 = isA
        ? (const char*)xh + (size_t)(mbase  + (wid & 3) * 64 + 2 * q8 + srow2) * 1024
              + sslot * 16
        : (const char*)ch + (size_t)(nstart + (wid & 3) * 64 + 2 * q8 + srow2) * 1024
              + sslot * 16;
    const int ldsbase = (isA ? 0 : 16384) + (wid & 3) * 4096;  // wave-uniform

    // slab g = ns*16 + kc:  col off = kc*64 B ; B adds ns*262144 (256 rows x 1KB)
    // STAGE2 issues gloads i0, i0+1 (16 rows each) of slab g into ring[g&3].
#define STAGE2(g, i0) do {                                                   \
        char* lb_ = smem + ((g) & 3) * 32768 + ldsbase;                      \
        const char* gs_ = gs0 + (isA ? 0 : (size_t)((g) >> 4) * 262144)      \
                          + ((g) & 15) * 64;                                 \
        gload_lds16(gs_ + (size_t)(i0) * 16384, lb_ + (i0) * 1024);          \
        gload_lds16(gs_ + (size_t)((i0) + 1) * 16384, lb_ + ((i0) + 1) * 1024); \
    } while (0)

    // ---- frag ds_read byte offsets (paired-row swizzle) ----
    // logical row = {wr*64|wc*128} + frag*16 + lr, slot = lg:
    // p = row>>1 -> line, p&7 = lr>>1; s' = (lg + 4*(lr&1)) ^ (lr>>1).
    const int lrh = lr >> 1;                                   // 0..7
    const int swz16 = ((lg + 4 * (lr & 1)) ^ lrh) * 16;
    const int aoff0 = (wr * 32 + lrh) * 128 + swz16;           // A frag m: +m*1024
    const int boff0 = 16384 + (wc * 64 + lrh) * 128 + swz16;   // B frag n: +n*1024

    // ---- per-thread running top-2 per (m,j), packed u32 ----
    u32 top2a[16], top2b[16];
#pragma unroll
    for (int s = 0; s < 16; ++s) { top2a[s] = ~0u; top2b[s] = ~0u; }

    f32x4 acc[4][8];
#pragma unroll
    for (int m = 0; m < 4; ++m)
#pragma unroll
        for (int n = 0; n < 8; ++n)
            acc[m][n] = (f32x4){0.f, 0.f, 0.f, 0.f};

    // subtile epilogue: fold 8 candidates/(m,j) into per-thread top-2; reset acc.
    auto epilogue = [&](int ns) {
        float e2v[8];
#pragma unroll
        for (int n = 0; n < 8; ++n)
            e2v[n] = 0.5f * e2s[ns * 256 + wc * 128 + n * 16 + lr];
        const u32 base10 = ((u32)ns << 8) | ((u32)wc << 7) | (u32)lr;
#pragma unroll
        for (int m = 0; m < 4; ++m) {
#pragma unroll
            for (int j = 0; j < 4; ++j) {
                const int s = m * 4 + j;
                u32 t1 = top2a[s], t2 = top2b[s];
#pragma unroll
                for (int n = 0; n < 8; ++n) {
                    float d = fmaxf(e2v[n] - acc[m][n][j], 1.0f);
                    u32 p = (__float_as_uint(d) & 0xFFFFFC00u) | (base10 + ((u32)n << 4));
                    u32 mx = t1 > p ? t1 : p;
                    t1 = t1 < p ? t1 : p;
                    t2 = t2 < mx ? t2 : mx;
                }
                top2a[s] = t1; top2b[s] = t2;
            }
        }
#pragma unroll
        for (int m = 0; m < 4; ++m)
#pragma unroll
            for (int n = 0; n < 8; ++n)
                acc[m][n] = (f32x4){0.f, 0.f, 0.f, 0.f};
    };

    // 4-MFMA micro-cluster: one A frag x 4 B frags (setprio-wrapped)
#define MFMA4(AF, BF, M, NOFF)                                               \
        __builtin_amdgcn_s_setprio(1);                                       \
        _Pragma("unroll")                                                    \
        for (int n = 0; n < 4; ++n)                                          \
            acc[M][(NOFF) + n] = __builtin_amdgcn_mfma_f32_16x16x32_f16(     \
                AF, BF[n], acc[M][(NOFF) + n], 0, 0, 0);                     \
        __builtin_amdgcn_s_setprio(0);

#define SB __builtin_amdgcn_sched_barrier(0)

    // prologue: stage slabs 0,1,2 (12 gloads/wave); wait slab 0 only (vmcnt(8)).
    STAGE2(0, 0); STAGE2(0, 2);
    STAGE2(1, 0); STAGE2(1, 2);
    STAGE2(2, 0); STAGE2(2, 2);
    asm volatile("s_waitcnt vmcnt(8)" ::: "memory");
    __builtin_amdgcn_s_barrier();
    SB;

#pragma unroll 1
    for (int s = 0; s < 64; ++s) {                 // slab s = ns*16 + kc
        const char* base = smem + (s & 3) * 32768;
        f16x8 af0, af1, af2, af3, bf[4], bg[4];

        // micro 0: minimal first-cluster reads (5)
        af0 = *(const f16x8*)(base + aoff0);
#pragma unroll
        for (int n = 0; n < 4; ++n)
            bf[n] = *(const f16x8*)(base + boff0 + n * 1024);
        SB;
        // micro 1: read af1 + stage half 1; MFMA m0 x bf
        af1 = *(const f16x8*)(base + aoff0 + 1024);
        if (s < 61) STAGE2(s + 3, 0);
        SB;
        MFMA4(af0, bf, 0, 0)
        SB;
        // micro 2: read af2; MFMA m1 x bf
        af2 = *(const f16x8*)(base + aoff0 + 2048);
        SB;
        MFMA4(af1, bf, 1, 0)
        SB;
        // micro 3: read af3; MFMA m2 x bf
        af3 = *(const f16x8*)(base + aoff0 + 3072);
        SB;
        MFMA4(af2, bf, 2, 0)
        SB;
        // micro 4: read bg0..3 + stage half 2; MFMA m3 x bf
#pragma unroll
        for (int n = 0; n < 4; ++n)
            bg[n] = *(const f16x8*)(base + boff0 + (4 + n) * 1024);
        if (s < 61) STAGE2(s + 3, 2);
        SB;
        MFMA4(af3, bf, 3, 0)
        SB;
        // micro 5-7: MFMA m0..m3 x bg (no reads left; LDS free for other waves)
        MFMA4(af0, bg, 0, 4)
        SB;
        MFMA4(af1, bg, 1, 4)
        SB;
        MFMA4(af2, bg, 2, 4)
        MFMA4(af3, bg, 3, 4)
        SB;

        // ---- slab end: counted wait (never drains the pipeline) ----
        // vmcnt(8): drains slab s+1's 4 loads (issued 3 slabs ago); s+2, s+3
        // stay in flight across the barrier. lgkmcnt(0): all reads of
        // ring[s&3] done before s+4's stage may overwrite it.
        if (s < 61)       asm volatile("s_waitcnt vmcnt(8)" ::: "memory");
        else if (s == 61) asm volatile("s_waitcnt vmcnt(4)" ::: "memory");
        else              asm volatile("s_waitcnt vmcnt(0)" ::: "memory");
        asm volatile("s_waitcnt lgkmcnt(0)" ::: "memory");
        SB;
        __builtin_amdgcn_s_barrier();
        SB;
        if ((s & 15) == 15) epilogue(s >> 4);      // registers + LDS e2s only
    }
#undef STAGE2
#undef MFMA4
#undef SB

    // ---- final cross-lane sorted-2 merge (once), write per-query stop table ----
#pragma unroll
    for (int m = 0; m < 4; ++m) {
#pragma unroll
        for (int j = 0; j < 4; ++j) {
            const int s = m * 4 + j;
            u32 t1 = top2a[s], t2 = top2b[s];
#pragma unroll
            for (int st = 1; st < 16; st <<= 1) {
                u32 o1 = __shfl_xor(t1, st);
                u32 o2 = __shfl_xor(t2, st);
                u32 mx = t1 > o1 ? t1 : o1;
                u32 sel = t1 < o1 ? t2 : o2;
                u32 n2 = mx < sel ? mx : sel;
                t1 = t1 < o1 ? t1 : o1;
                t2 = t2 < n2 ? t2 : n2;
            }
            if (lr == 0) {   // unique owner: 4 lanes (lg) x distinct ql
                int ql = wr * 64 + m * 16 + lg * 4 + j;
                stop[ql][wc][0] = t1; stop[ql][wc][1] = t2;
            }
        }
    }

    // ---- block epilogue: merge wc halves, decode, chain-push global top-3 ----
    __syncthreads();
    if (tid < 256) {
        u32 a1 = stop[tid][0][0], a2 = stop[tid][0][1];
        u32 b1 = stop[tid][1][0], b2 = stop[tid][1][1];
        u32 f1 = a1 < b1 ? a1 : b1;
        u32 mx = a1 > b1 ? a1 : b1;
        u32 sel = a1 < b1 ? a2 : b2;
        u32 f2 = mx < sel ? mx : sel;
        int q = mbase + tid;
        u64 p1 = ((u64)(f1 & 0xFFFFFC00u) << 32) | (u32)(nstart + (f1 & 0x3FFu));
        u64 p2 = ((u64)(f2 & 0xFFFFFC00u) << 32) | (u32)(nstart + (f2 & 0x3FFu));
        u64* As = slots + q;
        u64* Bs = slots + BT_ + q;
        u64* Cs = slots + 2 * BT_ + q;
        u64 old = atomicMin(As, p1);
        u64 v = umax64(old, p1);          // displaced value continues down
        old = atomicMin(Bs, v);
        u64 v2 = umax64(old, v);
        atomicMin(Cs, v2);
        old = atomicMin(Bs, p2);
        v = umax64(old, p2);
        atomicMin(Cs, v);
    }
}

// ---------------- exact rescore of global top-3 candidates ----------------
__global__ __launch_bounds__(256)
void k_rescore(const _Float16* __restrict__ xh, const _Float16* __restrict__ xl,
               const float* __restrict__ cb, const float* __restrict__ e2,
               const u64* __restrict__ slots,
               u32* __restrict__ final_idx, float* __restrict__ out_idx) {
    const int wid = threadIdx.x >> 6, lane = threadIdx.x & 63;
    const int q = blockIdx.x * 4 + wid;
    u64 a = slots[q], b = slots[BT_ + q], c = slots[2 * BT_ + q];
    u32 i1 = (u32)a, i2 = (u32)b, i3 = (u32)c;
    float d1 = __uint_as_float((u32)(a >> 32));  // scaled (0.5x) screened keys
    float d2 = __uint_as_float((u32)(b >> 32));
    u32 win = i1;
    if (!(d2 - d1 > 0.75f)) {            // margin test (scaled err bound << 0.75)
        float xr[8];
        f16x8 hv = *(const f16x8*)(xh + (size_t)q * D_ + lane * 8);
        f16x8 lv = *(const f16x8*)(xl + (size_t)q * D_ + lane * 8);
#pragma unroll
        for (int i = 0; i < 8; ++i) xr[i] = (float)hv[i] + (float)lv[i];
        u32 idxs[3] = {i1, i2, i3};
        float key[3];
#pragma unroll 1
        for (int cnd = 0; cnd < 3; ++cnd) {
            const float4* cr = (const float4*)(cb + (size_t)idxs[cnd] * D_ + lane * 8);
            float4 c0 = cr[0], c1 = cr[1];
            float s = xr[0] * c0.x;
            s = fmaf(xr[1], c0.y, s); s = fmaf(xr[2], c0.z, s); s = fmaf(xr[3], c0.w, s);
            s = fmaf(xr[4], c1.x, s); s = fmaf(xr[5], c1.y, s);
            s = fmaf(xr[6], c1.z, s); s = fmaf(xr[7], c1.w, s);
#pragma unroll
            for (int st = 1; st < 64; st <<= 1) s += __shfl_xor(s, st);
            key[cnd] = e2[idxs[cnd]] - 2.f * s;
        }
        float bk = key[0]; win = idxs[0];
#pragma unroll
        for (int cnd = 1; cnd < 3; ++cnd) {
            if (key[cnd] < bk || (key[cnd] == bk && idxs[cnd] < win)) {
                bk = key[cnd]; win = idxs[cnd];
            }
        }
    }
    if (lane == 0) { final_idx[q] = win; out_idx[q] = (float)win; }
}

// ---------------- fp32 fallback GEMM+argmin (used only if ws too small) ----------
#define MB 64
#define NB 64
#define KC 32
#define FNSPLIT 2
#define KPER (K_ / FNSPLIT)
__global__ __launch_bounds__(256, 2)
void k_argmin_f32(const float* __restrict__ x, const float* __restrict__ cb,
                  const float* __restrict__ e2, u64* __restrict__ slots) {
    __shared__ float xs[KC][MB + 4];
    __shared__ float es[KC][NB + 4];
    __shared__ u64 red[MB];
    const int tid = threadIdx.x;
    const int tx = tid & 15, ty = tid >> 4;
    const int rowtile = blockIdx.x;
    const int b = rowtile >> 5;
    const int tbase = (rowtile & 31) * MB;
    const int nstart = blockIdx.y * KPER;
    if (tid < MB) red[tid] = ~0ull;
    float bestv[4]; int besti[4];
#pragma unroll
    for (int i = 0; i < 4; ++i) { bestv[i] = 3.4e38f; besti[i] = 0; }
    const int sm = tid & 63, sg = tid >> 6;
    const float* xbase = x + (size_t)b * D_ * T_ + (tbase + sm);
    for (int nb = 0; nb < KPER; nb += NB) {
        float acc[4][4];
#pragma unroll
        for (int i = 0; i < 4; ++i)
#pragma unroll
            for (int j = 0; j < 4; ++j) acc[i][j] = 0.f;
        for (int kc = 0; kc < D_; kc += KC) {
            __syncthreads();
#pragma unroll
            for (int r = 0; r < 8; ++r) {
                int dd = sg * 8 + r;
                xs[dd][sm] = xbase[(size_t)(kc + dd) * T_];
            }
            const float* crow = cb + (size_t)(nstart + nb + sm) * D_ + kc + sg * 8;
            float4 c0 = *(const float4*)(crow);
            float4 c1 = *(const float4*)(crow + 4);
            es[sg * 8 + 0][sm] = c0.x; es[sg * 8 + 1][sm] = c0.y;
            es[sg * 8 + 2][sm] = c0.z; es[sg * 8 + 3][sm] = c0.w;
            es[sg * 8 + 4][sm] = c1.x; es[sg * 8 + 5][sm] = c1.y;
            es[sg * 8 + 6][sm] = c1.z; es[sg * 8 + 7][sm] = c1.w;
            __syncthreads();
#pragma unroll
            for (int dd = 0; dd < KC; ++dd) {
                float4 a = *(const float4*)&xs[dd][tx * 4];
                float4 e = *(const float4*)&es[dd][ty * 4];
                acc[0][0] = fmaf(a.x, e.x, acc[0][0]); acc[0][1] = fmaf(a.x, e.y, acc[0][1]);
                acc[0][2] = fmaf(a.x, e.z, acc[0][2]); acc[0][3] = fmaf(a.x, e.w, acc[0][3]);
                acc[1][0] = fmaf(a.y, e.x, acc[1][0]); acc[1][1] = fmaf(a.y, e.y, acc[1][1]);
                acc[1][2] = fmaf(a.y, e.z, acc[1][2]); acc[1][3] = fmaf(a.y, e.w, acc[1][3]);
                acc[2][0] = fmaf(a.z, e.x, acc[2][0]); acc[2][1] = fmaf(a.z, e.y, acc[2][1]);
                acc[2][2] = fmaf(a.z, e.z, acc[2][2]); acc[2][3] = fmaf(a.z, e.w, acc[2][3]);
                acc[3][0] = fmaf(a.w, e.x, acc[3][0]); acc[3][1] = fmaf(a.w, e.y, acc[3][1]);
                acc[3][2] = fmaf(a.w, e.z, acc[3][2]); acc[3][3] = fmaf(a.w, e.w, acc[3][3]);
            }
        }
#pragma unroll
        for (int j = 0; j < 4; ++j) {
            int c = nstart + nb + ty * 4 + j;
            float ec = e2[c];
#pragma unroll
            for (int i = 0; i < 4; ++i) {
                float dist = fmaf(-2.f, acc[i][j], ec);
                if (dist < bestv[i]) { bestv[i] = dist; besti[i] = c; }
            }
        }
    }
    __syncthreads();
#pragma unroll
    for (int i = 0; i < 4; ++i) {
        u64 p = ((u64)fkey(bestv[i]) << 32) | (u32)besti[i];
        atomicMin(&red[tx * 4 + i], p);
    }
    __syncthreads();
    if (tid < MB) atomicMin(&slots[b * T_ + tbase + tid], red[tid]);
}

// fallback finalize: slot A -> final_idx / out_idx
__global__ __launch_bounds__(256)
void k_finalize(const u64* __restrict__ slots,
                u32* __restrict__ final_idx, float* __restrict__ out_idx) {
    int q = blockIdx.x * 256 + threadIdx.x;
    u32 idx = (u32)slots[q];
    final_idx[q] = idx;
    out_idx[q] = (float)idx;
}

// ---------------- gather quantized + loss (fused: one atomicAdd per block) ---------
__global__ __launch_bounds__(256)
void k_gather(const float* __restrict__ x, const float* __restrict__ cb,
              const u32* __restrict__ final_idx,
              float* __restrict__ out_q, float* __restrict__ out_loss) {
    int tid = threadIdx.x;
    int btg = blockIdx.x * 256 + tid;
    int b = btg >> 11, t = btg & (T_ - 1);
    int dch = blockIdx.y;
    u32 idx = final_idx[btg];
    const float* crow = cb + (size_t)idx * D_;
    size_t xoff = (size_t)b * D_ * T_ + t;
    float ls = 0.f;
#pragma unroll 4
    for (int dd = 0; dd < 64; ++dd) {
        int d = dch * 64 + dd;
        float q = crow[d];
        size_t o = xoff + (size_t)d * T_;
        float xv = x[o];
        out_q[o] = q;
        float df = q - xv;
        ls = fmaf(df, df, ls);
    }
    __shared__ float rs[256];
    rs[tid] = ls;
    __syncthreads();
    for (int s = 128; s > 0; s >>= 1) {
        if (tid < s) rs[tid] += rs[tid + s];
        __syncthreads();
    }
    if (tid == 0) atomicAdd(out_loss, 0.25f * rs[0] / (float)NQ_);
}

extern "C" void kernel_launch(void* const* d_in, const int* in_sizes, int n_in,
                              void* d_out, int out_size, void* d_ws, size_t ws_size,
                              hipStream_t stream) {
    const float* x  = (const float*)d_in[0];
    const float* cb = (const float*)d_in[1];

    float* out_q    = (float*)d_out;
    float* out_idx  = out_q + NQ_;
    float* out_loss = out_idx + BT_;

    char* ws = (char*)d_ws;
    u64* slots = (u64*)(ws + WS_SLOTS_OFF);
    u32* fidx = (u32*)(ws + WS_FIDX_OFF);
    float* e2 = (float*)(ws + WS_E2_OFF);

    hipMemsetAsync(slots, 0xFF, (size_t)3 * BT_ * 8, stream);
    hipMemsetAsync(out_loss, 0, sizeof(float), stream);

    if (ws_size >= WS_NEEDED) {
        _Float16* xhp = (_Float16*)(ws + WS_XH_OFF);
        _Float16* xlp = (_Float16*)(ws + WS_XL_OFF);
        _Float16* chp = (_Float16*)(ws + WS_CH_OFF);
        k_prepcb<<<dim3(K_ / 4), dim3(256), 0, stream>>>(cb, chp, e2);
        k_splitx<<<dim3(T_ / 64, D_ / 64, B_), dim3(256), 0, stream>>>(x, xhp, xlp);
        k_hi_argmin<<<dim3(512), dim3(512), 0, stream>>>(xhp, chp, e2, slots);
        k_rescore<<<dim3(BT_ / 4), dim3(256), 0, stream>>>(xhp, xlp, cb, e2, slots,
                                                           fidx, out_idx);
    } else {
        k_e2<<<dim3(K_ / 256), dim3(256), 0, stream>>>(cb, e2);
        k_argmin_f32<<<dim3(BT_ / MB, FNSPLIT), dim3(256), 0, stream>>>(x, cb, e2, slots);
        k_finalize<<<dim3(BT_ / 256), dim3(256), 0, stream>>>(slots, fidx, out_idx);
    }

    k_gather<<<dim3(BT_ / 256, D_ / 64), dim3(256), 0, stream>>>(x, cb, fidx,
                                                                 out_q, out_loss);
}

// Round 11
// 200.163 us; speedup vs baseline: 1.0264x; 1.0264x over previous
//
#include <hip/hip_runtime.h>
#include <cstdint>
#include <cstddef>

// Problem constants (fixed by reference setup_inputs)
#define B_   8
#define D_   512
#define T_   2048
#define K_   8192
#define BT_  (B_ * T_)               // 16384 queries
#define NQ_  ((size_t)B_ * D_ * T_)  // 8388608 quantized elements

typedef _Float16 f16x8 __attribute__((ext_vector_type(8)));
typedef _Float16 f16x4 __attribute__((ext_vector_type(4)));
typedef float    f32x4 __attribute__((ext_vector_type(4)));
typedef unsigned long long u64;
typedef unsigned int u32;

// ws layout (bytes)
#define WS_SLOTS_OFF    0                        // u64[3*16384] = 393216
#define WS_FIDX_OFF     393216                   // u32[16384]   = 65536
#define WS_PART_OFF     458752                   // f32[512] (unused, kept for layout)
#define WS_E2_OFF       460800                   // f32[8192]
#define WS_XH_OFF       524288                   // f16[BT*512]  = 16777216
#define WS_XL_OFF       (WS_XH_OFF + 16777216)
#define WS_CH_OFF       (WS_XL_OFF + 16777216)   // f16[K*512]   = 8388608
#define WS_NEEDED       ((size_t)WS_CH_OFF + 8388608)   // ~42.5 MB

__device__ __forceinline__ void gload_lds16(const void* g, void* l) {
    __builtin_amdgcn_global_load_lds(
        (const __attribute__((address_space(1))) void*)g,
        (__attribute__((address_space(3))) void*)l, 16, 0, 0);
}

// monotone float -> uint key (handles negatives; preserves <) — fallback path only
__device__ __forceinline__ u32 fkey(float f) {
    u32 u = __float_as_uint(f);
    u ^= (u32)((int)u >> 31) | 0x80000000u;
    return u;
}
__device__ __forceinline__ u64 umin64(u64 a, u64 b) { return a < b ? a : b; }
__device__ __forceinline__ u64 umax64(u64 a, u64 b) { return a > b ? a : b; }

// ---------------- fused codebook prep: ch (f16 hi) + e2 in ONE cb pass ----------------
// wave per row: lane reads 8 floats (2x float4), writes f16x8, shfl-reduces e2.
__global__ __launch_bounds__(256) void k_prepcb(const float* __restrict__ cb,
                                                _Float16* __restrict__ ch,
                                                float* __restrict__ e2) {
    const int wid = threadIdx.x >> 6, lane = threadIdx.x & 63;
    const int row = blockIdx.x * 4 + wid;                    // grid 2048
    const float4* src = (const float4*)(cb + (size_t)row * D_ + lane * 8);
    float4 a = src[0], b = src[1];
    f16x8 h;
    h[0] = (_Float16)a.x; h[1] = (_Float16)a.y;
    h[2] = (_Float16)a.z; h[3] = (_Float16)a.w;
    h[4] = (_Float16)b.x; h[5] = (_Float16)b.y;
    h[6] = (_Float16)b.z; h[7] = (_Float16)b.w;
    *(f16x8*)(ch + (size_t)row * D_ + lane * 8) = h;
    float s = a.x * a.x;
    s = fmaf(a.y, a.y, s); s = fmaf(a.z, a.z, s); s = fmaf(a.w, a.w, s);
    s = fmaf(b.x, b.x, s); s = fmaf(b.y, b.y, s);
    s = fmaf(b.z, b.z, s); s = fmaf(b.w, b.w, s);
#pragma unroll
    for (int st = 1; st < 64; st <<= 1) s += __shfl_xor(s, st);
    if (lane == 0) e2[row] = s;
}

// ---------------- e2 only (fallback path, when ws can't hold ch) ----------------
__global__ __launch_bounds__(256) void k_e2(const float* __restrict__ cb,
                                            float* __restrict__ e2) {
    int k = blockIdx.x * 256 + threadIdx.x;
    const float4* row = (const float4*)(cb + (size_t)k * D_);
    float s = 0.f;
#pragma unroll 4
    for (int i = 0; i < D_ / 4; ++i) {
        float4 v = row[i];
        s = fmaf(v.x, v.x, s); s = fmaf(v.y, v.y, s);
        s = fmaf(v.z, v.z, s); s = fmaf(v.w, v.w, s);
    }
    e2[k] = s;
}

// ---------------- transpose+split x: [B,D,T] fp32 -> [BT,D] f16 hi/lo ----------------
// reads vectorized: 4 x float4 (64B contiguous per thread); writes coalesced over dl.
__global__ __launch_bounds__(256) void k_splitx(const float* __restrict__ x,
                                                _Float16* __restrict__ xh,
                                                _Float16* __restrict__ xl) {
    int b  = blockIdx.z;
    int d0 = blockIdx.y * 64;
    int t0 = blockIdx.x * 64;
    int dl = threadIdx.x & 63;
    int tq = threadIdx.x >> 6;
    const float* px = x + ((size_t)b * D_ + (d0 + dl)) * T_ + t0 + tq * 16;
#pragma unroll
    for (int i = 0; i < 4; ++i) {
        float4 v = *(const float4*)(px + i * 4);
#pragma unroll
        for (int j = 0; j < 4; ++j) {
            float vv = (j == 0) ? v.x : (j == 1) ? v.y : (j == 2) ? v.z : v.w;
            _Float16 h = (_Float16)vv;
            float lo = vv - (float)h;            // exact residual
            _Float16 l = (_Float16)lo;
            size_t row = (size_t)b * T_ + t0 + tq * 16 + i * 4 + j;
            xh[row * D_ + d0 + dl] = h;          // coalesced across lanes
            xl[row * D_ + d0 + dl] = l;
        }
    }
}

// ---------------- hi-only MFMA screening GEMM + deferred top-2 -> global top-3 ------
// screen key(q,c) = max(0.5*e2[c] - dot(xh_q, ch_c), 1.0) -> raw uint compare
// monotone. Packed u32 candidate: (bits & 0xFFFFFC00) | 10-bit local id
// (ns|wc|n|lr) == lexicographic first-min.
//
// FINAL (R11 = R9 = R5 verbatim; best measured: 155.5 us, MfmaUtil 39.7, 0
// conflicts). Session conclusion: R1-R10 falsified every scheduling/partition
// lever (per-phase barriers, barrier-free, reg pipelines, ring depth 2/3/4,
// 2-slab windows, +/- setprio, split barrier domains, 4-MFMA micro-clusters)
// — all land at 36-40% MfmaUtil = the serial sum of LDS (~1540 cy) and matrix
// (~1242 cy) per CU-slab. LDS read traffic (96KB/CU/slab) is INVARIANT to the
// wave-tile decomposition (A-dup x B-dup compensate exactly), so this is the
// structure's practical ceiling; breaking it requires fewer LDS bytes/FLOP
// (fp8/MX screen — breaks the exact top-3 capture bound) or 32x32x16 shape
// (~17% matrix-time, full layout rewrite). Plateau accepted.
// Structure: 256q x 1024c block, 512 thr / 8 waves (4m x 2n quadrants of 64q x
// 128c), K as 64 SLABS of BK=32 through a 4-DEEP LDS RING (4 x (A 16KB|B 16KB)).
// While computing slab s (ring[s&3]), stage slab s+3 as 2+2 gloads split across
// the two 16-MFMA phases; slab-end vmcnt(8) drains ONLY slab s+1 (issued 3 slabs
// earlier). One barrier per slab; lgkmcnt(0) guards ring reuse.
// Swizzle (proven 0 conflicts): row-pairs in 128-B lines; (row,slot4) -> s0 =
// slot + 4*(row&1), phys s' = s0 ^ ((row>>1)&7), byte = (row>>1)*128 + s'*16.
// Staging: gload_lds linear LDS dest + inverse-swizzled per-lane GLOBAL source
// (lane L: q=L>>3, u=(L&7)^q -> row 2q+(u>>2), slot u&3) — both-sides involution.
// e2 staged to LDS once; subtile epilogue (every 16 slabs) is reg + LDS e2s only.
__global__ __launch_bounds__(512, 2)
void k_hi_argmin(const _Float16* __restrict__ xh, const _Float16* __restrict__ ch,
                 const float* __restrict__ e2, u64* __restrict__ slots) {
    __shared__ char smem[131072];                // ring of 4 x (A 16KB | B 16KB)
    __shared__ u32 stop[256][2][2];              // per-query per-wc top-2 (packed u32)
    __shared__ float e2s[1024];                  // this block's e2 slice

    const int tid = threadIdx.x;
    // grid 512 = 8 xcd x 8 mtiles x 8 nsplit. XCD gets contiguous m-range (A L2-resident).
    const int xcd = blockIdx.x & 7;
    const int bi  = blockIdx.x >> 3;             // 0..63
    const int m_  = bi >> 3;                     // 0..7
    const int nblk = bi & 7;                     // 0..7
    const int mbase  = (xcd * 8 + m_) * 256;
    const int nstart = nblk * 1024;              // this block scans 1024 codes (4 subtiles)

    const int lane = tid & 63;
    const int wid  = tid >> 6;                   // 0..7
    const int wr = wid & 3, wc = wid >> 2;       // wave quadrant 64q x 128c
    const int lr = lane & 15, lg = lane >> 4;

    // init per-block top-2 table + stage e2 slice (no VMEM later in the loop)
    {
        u32* p = (u32*)stop;
        p[tid] = ~0u; p[tid + 512] = ~0u;
        *(float2*)&e2s[tid * 2] = *(const float2*)&e2[nstart + tid * 2];
    }
    __syncthreads();

    // ---- staging geometry: per wave 64 rows x 64 B per slab; 4 gloads x 16 rows ----
    // inverse-swizzled global source: lane L -> q=L>>3, u=(L&7)^q,
    // row = 2q + (u>>2), slot = u&3. (LDS dest stays linear: base + L*16.)
    const bool isA = wid < 4;
    const int q8 = lane >> 3;                    // 0..7
    const int u8 = (lane & 7) ^ q8;
    const int srow2 = (u8 >> 2) & 1;
    const int sslot = u8 & 3;
    const char* gs0 = isA
        ? (const char*)xh + (size_t)(mbase  + (wid & 3) * 64 + 2 * q8 + srow2) * 1024
              + sslot * 16
        : (const char*)ch + (size_t)(nstart + (wid & 3) * 64 + 2 * q8 + srow2) * 1024
              + sslot * 16;
    const int ldsbase = (isA ? 0 : 16384) + (wid & 3) * 4096;  // wave-uniform

    // slab g = ns*16 + kc:  col off = kc*64 B ; B adds ns*262144 (256 rows x 1KB)
    // STAGE2 issues gloads i0, i0+1 (16 rows each) of slab g into ring[g&3].
#define STAGE2(g, i0) do {                                                   \
        char* lb_ = smem + ((g) & 3) * 32768 + ldsbase;                      \
        const char* gs_ = gs0 + (isA ? 0 : (size_t)((g) >> 4) * 262144)      \
                          + ((g) & 15) * 64;                                 \
        gload_lds16(gs_ + (size_t)(i0) * 16384, lb_ + (i0) * 1024);          \
        gload_lds16(gs_ + (size_t)((i0) + 1) * 16384, lb_ + ((i0) + 1) * 1024); \
    } while (0)

    // ---- frag ds_read byte offsets (paired-row swizzle) ----
    // logical row = {wr*64|wc*128} + frag*16 + lr, slot = lg:
    // p = row>>1 -> line, p&7 = lr>>1; s' = (lg + 4*(lr&1)) ^ (lr>>1).
    const int lrh = lr >> 1;                                   // 0..7
    const int swz16 = ((lg + 4 * (lr & 1)) ^ lrh) * 16;
    const int aoff0 = (wr * 32 + lrh) * 128 + swz16;           // A frag m: +m*1024
    const int boff0 = 16384 + (wc * 64 + lrh) * 128 + swz16;   // B frag n: +n*1024

    // ---- per-thread running top-2 per (m,j), packed u32 ----
    u32 top2a[16], top2b[16];
#pragma unroll
    for (int s = 0; s < 16; ++s) { top2a[s] = ~0u; top2b[s] = ~0u; }

    f32x4 acc[4][8];
#pragma unroll
    for (int m = 0; m < 4; ++m)
#pragma unroll
        for (int n = 0; n < 8; ++n)
            acc[m][n] = (f32x4){0.f, 0.f, 0.f, 0.f};

    // subtile epilogue: fold 8 candidates/(m,j) into per-thread top-2; reset acc.
    auto epilogue = [&](int ns) {
        float e2v[8];
#pragma unroll
        for (int n = 0; n < 8; ++n)
            e2v[n] = 0.5f * e2s[ns * 256 + wc * 128 + n * 16 + lr];
        const u32 base10 = ((u32)ns << 8) | ((u32)wc << 7) | (u32)lr;
#pragma unroll
        for (int m = 0; m < 4; ++m) {
#pragma unroll
            for (int j = 0; j < 4; ++j) {
                const int s = m * 4 + j;
                u32 t1 = top2a[s], t2 = top2b[s];
#pragma unroll
                for (int n = 0; n < 8; ++n) {
                    float d = fmaxf(e2v[n] - acc[m][n][j], 1.0f);
                    u32 p = (__float_as_uint(d) & 0xFFFFFC00u) | (base10 + ((u32)n << 4));
                    u32 mx = t1 > p ? t1 : p;
                    t1 = t1 < p ? t1 : p;
                    t2 = t2 < mx ? t2 : mx;
                }
                top2a[s] = t1; top2b[s] = t2;
            }
        }
#pragma unroll
        for (int m = 0; m < 4; ++m)
#pragma unroll
            for (int n = 0; n < 8; ++n)
                acc[m][n] = (f32x4){0.f, 0.f, 0.f, 0.f};
    };

#define MFMA16(AF, BF, NOFF)                                                 \
        __builtin_amdgcn_s_setprio(1);                                       \
        _Pragma("unroll")                                                    \
        for (int m = 0; m < 4; ++m)                                          \
            _Pragma("unroll")                                                \
            for (int n = 0; n < 4; ++n)                                      \
                acc[m][(NOFF) + n] = __builtin_amdgcn_mfma_f32_16x16x32_f16( \
                    AF[m], BF[n], acc[m][(NOFF) + n], 0, 0, 0);              \
        __builtin_amdgcn_s_setprio(0);

#define SB __builtin_amdgcn_sched_barrier(0)

    // prologue: stage slabs 0,1,2 (12 gloads/wave); wait slab 0 only (vmcnt(8)).
    STAGE2(0, 0); STAGE2(0, 2);
    STAGE2(1, 0); STAGE2(1, 2);
    STAGE2(2, 0); STAGE2(2, 2);
    asm volatile("s_waitcnt vmcnt(8)" ::: "memory");
    __builtin_amdgcn_s_barrier();
    SB;

#pragma unroll 1
    for (int s = 0; s < 64; ++s) {                 // slab s = ns*16 + kc
        const char* base = smem + (s & 3) * 32768;
        f16x8 af[4], bf[4], bg[4];

        // ---- phase 0: A frags + B n0-3; stage slab s+3 half 1 ----
#pragma unroll
        for (int m = 0; m < 4; ++m)
            af[m] = *(const f16x8*)(base + aoff0 + m * 1024);
#pragma unroll
        for (int n = 0; n < 4; ++n)
            bf[n] = *(const f16x8*)(base + boff0 + n * 1024);
        if (s < 61) STAGE2(s + 3, 0);
        SB;
        MFMA16(af, bf, 0)
        SB;
        // ---- phase 1: B n4-7; stage slab s+3 half 2 ----
#pragma unroll
        for (int n = 0; n < 4; ++n)
            bg[n] = *(const f16x8*)(base + boff0 + (4 + n) * 1024);
        if (s < 61) STAGE2(s + 3, 2);
        SB;
        MFMA16(af, bg, 4)
        SB;

        // ---- slab end: counted wait (never drains the pipeline) ----
        // vmcnt(8): drains slab s+1's 4 loads (issued 3 slabs ago); s+2, s+3
        // stay in flight across the barrier. lgkmcnt(0): all reads of
        // ring[s&3] done before s+4's stage may overwrite it.
        if (s < 61)       asm volatile("s_waitcnt vmcnt(8)" ::: "memory");
        else if (s == 61) asm volatile("s_waitcnt vmcnt(4)" ::: "memory");
        else              asm volatile("s_waitcnt vmcnt(0)" ::: "memory");
        asm volatile("s_waitcnt lgkmcnt(0)" ::: "memory");
        SB;
        __builtin_amdgcn_s_barrier();
        SB;
        if ((s & 15) == 15) epilogue(s >> 4);      // registers + LDS e2s only
    }
#undef STAGE2
#undef MFMA16
#undef SB

    // ---- final cross-lane sorted-2 merge (once), write per-query stop table ----
#pragma unroll
    for (int m = 0; m < 4; ++m) {
#pragma unroll
        for (int j = 0; j < 4; ++j) {
            const int s = m * 4 + j;
            u32 t1 = top2a[s], t2 = top2b[s];
#pragma unroll
            for (int st = 1; st < 16; st <<= 1) {
                u32 o1 = __shfl_xor(t1, st);
                u32 o2 = __shfl_xor(t2, st);
                u32 mx = t1 > o1 ? t1 : o1;
                u32 sel = t1 < o1 ? t2 : o2;
                u32 n2 = mx < sel ? mx : sel;
                t1 = t1 < o1 ? t1 : o1;
                t2 = t2 < n2 ? t2 : n2;
            }
            if (lr == 0) {   // unique owner: 4 lanes (lg) x distinct ql
                int ql = wr * 64 + m * 16 + lg * 4 + j;
                stop[ql][wc][0] = t1; stop[ql][wc][1] = t2;
            }
        }
    }

    // ---- block epilogue: merge wc halves, decode, chain-push global top-3 ----
    __syncthreads();
    if (tid < 256) {
        u32 a1 = stop[tid][0][0], a2 = stop[tid][0][1];
        u32 b1 = stop[tid][1][0], b2 = stop[tid][1][1];
        u32 f1 = a1 < b1 ? a1 : b1;
        u32 mx = a1 > b1 ? a1 : b1;
        u32 sel = a1 < b1 ? a2 : b2;
        u32 f2 = mx < sel ? mx : sel;
        int q = mbase + tid;
        u64 p1 = ((u64)(f1 & 0xFFFFFC00u) << 32) | (u32)(nstart + (f1 & 0x3FFu));
        u64 p2 = ((u64)(f2 & 0xFFFFFC00u) << 32) | (u32)(nstart + (f2 & 0x3FFu));
        u64* As = slots + q;
        u64* Bs = slots + BT_ + q;
        u64* Cs = slots + 2 * BT_ + q;
        u64 old = atomicMin(As, p1);
        u64 v = umax64(old, p1);          // displaced value continues down
        old = atomicMin(Bs, v);
        u64 v2 = umax64(old, v);
        atomicMin(Cs, v2);
        old = atomicMin(Bs, p2);
        v = umax64(old, p2);
        atomicMin(Cs, v);
    }
}

// ---------------- exact rescore of global top-3 candidates ----------------
__global__ __launch_bounds__(256)
void k_rescore(const _Float16* __restrict__ xh, const _Float16* __restrict__ xl,
               const float* __restrict__ cb, const float* __restrict__ e2,
               const u64* __restrict__ slots,
               u32* __restrict__ final_idx, float* __restrict__ out_idx) {
    const int wid = threadIdx.x >> 6, lane = threadIdx.x & 63;
    const int q = blockIdx.x * 4 + wid;
    u64 a = slots[q], b = slots[BT_ + q], c = slots[2 * BT_ + q];
    u32 i1 = (u32)a, i2 = (u32)b, i3 = (u32)c;
    float d1 = __uint_as_float((u32)(a >> 32));  // scaled (0.5x) screened keys
    float d2 = __uint_as_float((u32)(b >> 32));
    u32 win = i1;
    if (!(d2 - d1 > 0.75f)) {            // margin test (scaled err bound << 0.75)
        float xr[8];
        f16x8 hv = *(const f16x8*)(xh + (size_t)q * D_ + lane * 8);
        f16x8 lv = *(const f16x8*)(xl + (size_t)q * D_ + lane * 8);
#pragma unroll
        for (int i = 0; i < 8; ++i) xr[i] = (float)hv[i] + (float)lv[i];
        u32 idxs[3] = {i1, i2, i3};
        float key[3];
#pragma unroll 1
        for (int cnd = 0; cnd < 3; ++cnd) {
            const float4* cr = (const float4*)(cb + (size_t)idxs[cnd] * D_ + lane * 8);
            float4 c0 = cr[0], c1 = cr[1];
            float s = xr[0] * c0.x;
            s = fmaf(xr[1], c0.y, s); s = fmaf(xr[2], c0.z, s); s = fmaf(xr[3], c0.w, s);
            s = fmaf(xr[4], c1.x, s); s = fmaf(xr[5], c1.y, s);
            s = fmaf(xr[6], c1.z, s); s = fmaf(xr[7], c1.w, s);
#pragma unroll
            for (int st = 1; st < 64; st <<= 1) s += __shfl_xor(s, st);
            key[cnd] = e2[idxs[cnd]] - 2.f * s;
        }
        float bk = key[0]; win = idxs[0];
#pragma unroll
        for (int cnd = 1; cnd < 3; ++cnd) {
            if (key[cnd] < bk || (key[cnd] == bk && idxs[cnd] < win)) {
                bk = key[cnd]; win = idxs[cnd];
            }
        }
    }
    if (lane == 0) { final_idx[q] = win; out_idx[q] = (float)win; }
}

// ---------------- fp32 fallback GEMM+argmin (used only if ws too small) ----------
#define MB 64
#define NB 64
#define KC 32
#define FNSPLIT 2
#define KPER (K_ / FNSPLIT)
__global__ __launch_bounds__(256, 2)
void k_argmin_f32(const float* __restrict__ x, const float* __restrict__ cb,
                  const float* __restrict__ e2, u64* __restrict__ slots) {
    __shared__ float xs[KC][MB + 4];
    __shared__ float es[KC][NB + 4];
    __shared__ u64 red[MB];
    const int tid = threadIdx.x;
    const int tx = tid & 15, ty = tid >> 4;
    const int rowtile = blockIdx.x;
    const int b = rowtile >> 5;
    const int tbase = (rowtile & 31) * MB;
    const int nstart = blockIdx.y * KPER;
    if (tid < MB) red[tid] = ~0ull;
    float bestv[4]; int besti[4];
#pragma unroll
    for (int i = 0; i < 4; ++i) { bestv[i] = 3.4e38f; besti[i] = 0; }
    const int sm = tid & 63, sg = tid >> 6;
    const float* xbase = x + (size_t)b * D_ * T_ + (tbase + sm);
    for (int nb = 0; nb < KPER; nb += NB) {
        float acc[4][4];
#pragma unroll
        for (int i = 0; i < 4; ++i)
#pragma unroll
            for (int j = 0; j < 4; ++j) acc[i][j] = 0.f;
        for (int kc = 0; kc < D_; kc += KC) {
            __syncthreads();
#pragma unroll
            for (int r = 0; r < 8; ++r) {
                int dd = sg * 8 + r;
                xs[dd][sm] = xbase[(size_t)(kc + dd) * T_];
            }
            const float* crow = cb + (size_t)(nstart + nb + sm) * D_ + kc + sg * 8;
            float4 c0 = *(const float4*)(crow);
            float4 c1 = *(const float4*)(crow + 4);
            es[sg * 8 + 0][sm] = c0.x; es[sg * 8 + 1][sm] = c0.y;
            es[sg * 8 + 2][sm] = c0.z; es[sg * 8 + 3][sm] = c0.w;
            es[sg * 8 + 4][sm] = c1.x; es[sg * 8 + 5][sm] = c1.y;
            es[sg * 8 + 6][sm] = c1.z; es[sg * 8 + 7][sm] = c1.w;
            __syncthreads();
#pragma unroll
            for (int dd = 0; dd < KC; ++dd) {
                float4 a = *(const float4*)&xs[dd][tx * 4];
                float4 e = *(const float4*)&es[dd][ty * 4];
                acc[0][0] = fmaf(a.x, e.x, acc[0][0]); acc[0][1] = fmaf(a.x, e.y, acc[0][1]);
                acc[0][2] = fmaf(a.x, e.z, acc[0][2]); acc[0][3] = fmaf(a.x, e.w, acc[0][3]);
                acc[1][0] = fmaf(a.y, e.x, acc[1][0]); acc[1][1] = fmaf(a.y, e.y, acc[1][1]);
                acc[1][2] = fmaf(a.y, e.z, acc[1][2]); acc[1][3] = fmaf(a.y, e.w, acc[1][3]);
                acc[2][0] = fmaf(a.z, e.x, acc[2][0]); acc[2][1] = fmaf(a.z, e.y, acc[2][1]);
                acc[2][2] = fmaf(a.z, e.z, acc[2][2]); acc[2][3] = fmaf(a.z, e.w, acc[2][3]);
                acc[3][0] = fmaf(a.w, e.x, acc[3][0]); acc[3][1] = fmaf(a.w, e.y, acc[3][1]);
                acc[3][2] = fmaf(a.w, e.z, acc[3][2]); acc[3][3] = fmaf(a.w, e.w, acc[3][3]);
            }
        }
#pragma unroll
        for (int j = 0; j < 4; ++j) {
            int c = nstart + nb + ty * 4 + j;
            float ec = e2[c];
#pragma unroll
            for (int i = 0; i < 4; ++i) {
                float dist = fmaf(-2.f, acc[i][j], ec);
                if (dist < bestv[i]) { bestv[i] = dist; besti[i] = c; }
            }
        }
    }
    __syncthreads();
#pragma unroll
    for (int i = 0; i < 4; ++i) {
        u64 p = ((u64)fkey(bestv[i]) << 32) | (u32)besti[i];
        atomicMin(&red[tx * 4 + i], p);
    }
    __syncthreads();
    if (tid < MB) atomicMin(&slots[b * T_ + tbase + tid], red[tid]);
}

// fallback finalize: slot A -> final_idx / out_idx
__global__ __launch_bounds__(256)
void k_finalize(const u64* __restrict__ slots,
                u32* __restrict__ final_idx, float* __restrict__ out_idx) {
    int q = blockIdx.x * 256 + threadIdx.x;
    u32 idx = (u32)slots[q];
    final_idx[q] = idx;
    out_idx[q] = (float)idx;
}

// ---------------- gather quantized + loss (fused: one atomicAdd per block) ---------
__global__ __launch_bounds__(256)
void k_gather(const float* __restrict__ x, const float* __restrict__ cb,
              const u32* __restrict__ final_idx,
              float* __restrict__ out_q, float* __restrict__ out_loss) {
    int tid = threadIdx.x;
    int btg = blockIdx.x * 256 + tid;
    int b = btg >> 11, t = btg & (T_ - 1);
    int dch = blockIdx.y;
    u32 idx = final_idx[btg];
    const float* crow = cb + (size_t)idx * D_;
    size_t xoff = (size_t)b * D_ * T_ + t;
    float ls = 0.f;
#pragma unroll 4
    for (int dd = 0; dd < 64; ++dd) {
        int d = dch * 64 + dd;
        float q = crow[d];
        size_t o = xoff + (size_t)d * T_;
        float xv = x[o];
        out_q[o] = q;
        float df = q - xv;
        ls = fmaf(df, df, ls);
    }
    __shared__ float rs[256];
    rs[tid] = ls;
    __syncthreads();
    for (int s = 128; s > 0; s >>= 1) {
        if (tid < s) rs[tid] += rs[tid + s];
        __syncthreads();
    }
    if (tid == 0) atomicAdd(out_loss, 0.25f * rs[0] / (float)NQ_);
}

extern "C" void kernel_launch(void* const* d_in, const int* in_sizes, int n_in,
                              void* d_out, int out_size, void* d_ws, size_t ws_size,
                              hipStream_t stream) {
    const float* x  = (const float*)d_in[0];
    const float* cb = (const float*)d_in[1];

    float* out_q    = (float*)d_out;
    float* out_idx  = out_q + NQ_;
    float* out_loss = out_idx + BT_;

    char* ws = (char*)d_ws;
    u64* slots = (u64*)(ws + WS_SLOTS_OFF);
    u32* fidx = (u32*)(ws + WS_FIDX_OFF);
    float* e2 = (float*)(ws + WS_E2_OFF);

    hipMemsetAsync(slots, 0xFF, (size_t)3 * BT_ * 8, stream);
    hipMemsetAsync(out_loss, 0, sizeof(float), stream);

    if (ws_size >= WS_NEEDED) {
        _Float16* xhp = (_Float16*)(ws + WS_XH_OFF);
        _Float16* xlp = (_Float16*)(ws + WS_XL_OFF);
        _Float16* chp = (_Float16*)(ws + WS_CH_OFF);
        k_prepcb<<<dim3(K_ / 4), dim3(256), 0, stream>>>(cb, chp, e2);
        k_splitx<<<dim3(T_ / 64, D_ / 64, B_), dim3(256), 0, stream>>>(x, xhp, xlp);
        k_hi_argmin<<<dim3(512), dim3(512), 0, stream>>>(xhp, chp, e2, slots);
        k_rescore<<<dim3(BT_ / 4), dim3(256), 0, stream>>>(xhp, xlp, cb, e2, slots,
                                                           fidx, out_idx);
    } else {
        k_e2<<<dim3(K_ / 256), dim3(256), 0, stream>>>(cb, e2);
        k_argmin_f32<<<dim3(BT_ / MB, FNSPLIT), dim3(256), 0, stream>>>(x, cb, e2, slots);
        k_finalize<<<dim3(BT_ / 256), dim3(256), 0, stream>>>(slots, fidx, out_idx);
    }

    k_gather<<<dim3(BT_ / 256, D_ / 64), dim3(256), 0, stream>>>(x, cb, fidx,
                                                                 out_q, out_loss);
}